// Round 6
// baseline (177.893 us; speedup 1.0000x reference)
//
#include <hip/hip_runtime.h>

#define K_KNOTS 1024
#define N_CTRL  1021
#define TABM    4096            // buckets; ~75% contain no knot
#define FREE_BIT 0x8000

typedef float vfloat4 __attribute__((ext_vector_type(4)));   // nontemporal-safe

// ---------------------------------------------------------------------------
// Kernel 1: rank sort of the 1024 knots (stable, tie-safe). 16 blocks x 64.
// ---------------------------------------------------------------------------
__global__ void sort_knots_kernel(const float* __restrict__ knots,
                                  float* __restrict__ ts) {
    __shared__ __align__(16) float kl[K_KNOTS];
    const int tid = threadIdx.x;
    const int gid = blockIdx.x * blockDim.x + tid;
    for (int i = tid; i < K_KNOTS / 4; i += blockDim.x)
        ((float4*)kl)[i] = ((const float4*)knots)[i];
    __syncthreads();
    const float my = kl[gid];
    int rank = 0;
    const float4* kl4 = (const float4*)kl;
#pragma unroll 8
    for (int j4 = 0; j4 < K_KNOTS / 4; ++j4) {
        const float4 v = kl4[j4];
        const int j = j4 * 4;
        rank += (v.x < my || (v.x == my && j + 0 < gid)) ? 1 : 0;
        rank += (v.y < my || (v.y == my && j + 1 < gid)) ? 1 : 0;
        rank += (v.z < my || (v.z == my && j + 2 < gid)) ? 1 : 0;
        rank += (v.w < my || (v.w == my && j + 3 < gid)) ? 1 : 0;
    }
    ts[rank] = my;
}

// ---------------------------------------------------------------------------
// Cubic in u = x - tref carried through the de Boor recursion (prep only,
// double precision to kill cancellation for tiny knot gaps).
// ---------------------------------------------------------------------------
struct PolyD { double c0, c1, c2, c3; };

__device__ __forceinline__ PolyD lerp_poly(const PolyD dl, const PolyD dr,
                                           double tl, double tr, double tref) {
    const double inv = 1.0 / (tr - tl);
    const double A = (tref - tl) * inv;
    const double e0 = dr.c0 - dl.c0, e1 = dr.c1 - dl.c1;
    const double e2 = dr.c2 - dl.c2, e3 = dr.c3 - dl.c3;
    PolyD o;
    o.c0 = dl.c0 + A * e0;
    o.c1 = dl.c1 + A * e1 + inv * e0;
    o.c2 = dl.c2 + A * e2 + inv * e1;
    o.c3 = dl.c3 + A * e3 + inv * e2;
    return o;
}

// cubic for interval s (ts[s-1] < x <= ts[s], s in [4,1020]) centered at tref
__device__ __forceinline__ float4 interval_poly(const float* tss,
                                                const float* __restrict__ c,
                                                int s, double tref) {
    const double T0 = tss[s - 3], T1 = tss[s - 2], T2 = tss[s - 1];
    const double T3 = tss[s],     T4 = tss[s + 1], T5 = tss[s + 2];
    PolyD d0 = {(double)c[s - 4], 0, 0, 0}, d1 = {(double)c[s - 3], 0, 0, 0};
    PolyD d2 = {(double)c[s - 2], 0, 0, 0}, d3 = {(double)c[s - 1], 0, 0, 0};
    d3 = lerp_poly(d2, d3, T2, T5, tref);   // r=1
    d2 = lerp_poly(d1, d2, T1, T4, tref);
    d1 = lerp_poly(d0, d1, T0, T3, tref);
    d3 = lerp_poly(d2, d3, T2, T4, tref);   // r=2
    d2 = lerp_poly(d1, d2, T1, T3, tref);
    d3 = lerp_poly(d2, d3, T2, T3, tref);   // r=3
    return make_float4((float)d3.c0, (float)d3.c1, (float)d3.c2, (float)d3.c3);
}

// ---------------------------------------------------------------------------
// Kernel 2 (prep), 20 blocks x 256:
//  threads 0..1023   -> coef[s]: interval cubic centered at grid point
//                       gm = m/4096, m = round(ts[s]*4096), m packed into the
//                       low 13 mantissa bits of c3 (<=2^-10 rel perturbation).
//                       Thread 0..7 also write the +inf scan pad after ts.
//  threads 1024..5119-> tab[b] = s_lo | FREE_BIT if no knot in [Lb-eps,Rb+eps)
//                       else s_lo (clamped) as the fallback scan start.
// ---------------------------------------------------------------------------
__device__ __forceinline__ int lower_bound_s(const float* tss, float v) {
    int lo = 0, hi = K_KNOTS;
    while (lo < hi) {
        const int mid = (lo + hi) >> 1;
        if (tss[mid] < v) lo = mid + 1; else hi = mid;
    }
    return lo;
}

__global__ void prep_kernel(float* __restrict__ ts,   // [K_KNOTS + 8] w/ pad
                            const float* __restrict__ c,
                            float4* __restrict__ coefI,
                            unsigned short* __restrict__ tab) {
    __shared__ float tss[K_KNOTS];
    const int tid = threadIdx.x;
    for (int i = tid; i < K_KNOTS; i += blockDim.x) tss[i] = ts[i];
    __syncthreads();

    const int g = blockIdx.x * blockDim.x + tid;   // 0..5119
    if (g < K_KNOTS) {
        if (g < 8) ts[K_KNOTS + g] = 1e30f;        // scan pad (eval-only)
        const int s = g;
        float4 out = make_float4(0.f, 0.f, 0.f, 0.f);
        if (s >= 4 && s <= 1020) {
            int m = (int)((double)tss[s] * (double)TABM + 0.5);
            m = m < 0 ? 0 : (m > TABM ? TABM : m);           // fits 13 bits
            const double gm = (double)m * (1.0 / (double)TABM);
            float4 p = interval_poly(tss, c, s, gm);
            const unsigned int wb =
                (__float_as_uint(p.w) & ~0x1FFFu) | (unsigned int)m;
            p.w = __uint_as_float(wb);
            out = p;
        }
        coefI[s] = out;
    } else {
        const int b = g - K_KNOTS;                 // 0..4095
        const float eps = 1e-6f;
        const float Lb = (float)b * (1.0f / (float)TABM) - eps;
        const float Rb = (float)(b + 1) * (1.0f / (float)TABM) + eps;
        const int lo1 = lower_bound_s(tss, Lb);
        const int lo2 = lower_bound_s(tss, Rb);
        const int sc = lo1 < 4 ? 4 : (lo1 > 1020 ? 1020 : lo1);  // safety clamp
        unsigned short h = (unsigned short)sc;
        if (lo1 == lo2 && lo1 >= 4 && lo1 <= 1020) h |= FREE_BIT;
        tab[b] = h;
    }
}

// ---------------------------------------------------------------------------
// Kernel 3: evaluation. Fast path (~75% of lanes): ds_read_u16 (tab) ->
// ds_read_b128 (coef) -> Horner; u = fma(m, -2^-12, x) from packed bits.
// Fallback (~25%): scan ts from s_lo via GLOBAL reads (4 KB stays L1-hot;
// dropping ts from LDS shrinks the block to 24 KB -> 6 blocks/CU = 24 waves).
// Domain guarantees x in (ts[3], ts[1020]) subset (0,1) -> b in [0,4095]
// without clamps, and the scan terminates at s <= 1020 (pad is belt+braces).
// ---------------------------------------------------------------------------
__device__ __forceinline__ float eval_one(float x,
                                          const unsigned short* __restrict__ tab,
                                          const float4* __restrict__ cs,
                                          const float* __restrict__ ts_g) {
    const int b = (int)(x * (float)TABM);
    const unsigned short h = tab[b];
    int s = h & 0x7FFF;
    if (!(h & FREE_BIT)) {
        float t = ts_g[s];
        while (t < x) { ++s; t = ts_g[s]; }   // expected ~1.3 iterations
    }
    const float4 e = cs[s];
    const int m = (int)(__float_as_uint(e.w) & 0x1FFFu);
    const float u = __builtin_fmaf((float)m, -1.0f / (float)TABM, x);
    return e.x + u * (e.y + u * (e.z + u * e.w));
}

__global__ __launch_bounds__(256, 6) void eval_kernel(
        const vfloat4* __restrict__ x4,
        const float* __restrict__ ts_g,
        const float4* __restrict__ coefI_g,
        const unsigned short* __restrict__ tab_g,
        vfloat4* __restrict__ out4, int n4) {
    __shared__ __align__(16) unsigned short tab_s[TABM];    // 8 KB
    __shared__ __align__(16) float4 coefI_s[K_KNOTS];       // 16 KB (24 KB tot)
    const int tid = threadIdx.x;

#pragma unroll
    for (int i = tid; i < TABM * 2 / 16; i += 256)
        ((uint4*)tab_s)[i] = ((const uint4*)tab_g)[i];
#pragma unroll
    for (int i = tid; i < K_KNOTS; i += 256) coefI_s[i] = coefI_g[i];
    __syncthreads();

    const int gid    = blockIdx.x * 256 + tid;
    const int stride = gridDim.x * 256;
    for (int i = gid; i < n4; i += 2 * stride) {
        const int i2 = i + stride;
        const bool has2 = i2 < n4;
        const vfloat4 xa = __builtin_nontemporal_load(&x4[i]);
        const vfloat4 xb = has2 ? __builtin_nontemporal_load(&x4[i2]) : xa;
        vfloat4 ra, rb;
        ra.x = eval_one(xa.x, tab_s, coefI_s, ts_g);
        ra.y = eval_one(xa.y, tab_s, coefI_s, ts_g);
        ra.z = eval_one(xa.z, tab_s, coefI_s, ts_g);
        ra.w = eval_one(xa.w, tab_s, coefI_s, ts_g);
        rb.x = eval_one(xb.x, tab_s, coefI_s, ts_g);
        rb.y = eval_one(xb.y, tab_s, coefI_s, ts_g);
        rb.z = eval_one(xb.z, tab_s, coefI_s, ts_g);
        rb.w = eval_one(xb.w, tab_s, coefI_s, ts_g);
        __builtin_nontemporal_store(ra, &out4[i]);
        if (has2) __builtin_nontemporal_store(rb, &out4[i2]);
    }
}

extern "C" void kernel_launch(void* const* d_in, const int* in_sizes, int n_in,
                              void* d_out, int out_size, void* d_ws, size_t ws_size,
                              hipStream_t stream) {
    const float* x     = (const float*)d_in[0];  // [16777216]
    const float* knots = (const float*)d_in[1];  // [1024] unsorted
    const float* c     = (const float*)d_in[2];  // [1021]
    float* out = (float*)d_out;

    // ws layout: ts @0 (4 KB + 32 B pad) | coefI @8K (16 KB) | tab @24K (8 KB)
    float*  ts_ws    = (float*)d_ws;
    float4* coefI_ws = (float4*)((char*)d_ws + 8192);
    unsigned short* tab_ws = (unsigned short*)((char*)d_ws + 8192 + 16384);

    sort_knots_kernel<<<16, 64, 0, stream>>>(knots, ts_ws);
    prep_kernel<<<(K_KNOTS + TABM) / 256, 256, 0, stream>>>(ts_ws, c, coefI_ws, tab_ws);

    const int n4 = out_size / 4;   // 4,194,304
    // 1536 blocks = 6 resident blocks/CU x 256 CUs (24 KB LDS -> 6 blocks/CU)
    eval_kernel<<<1536, 256, 0, stream>>>((const vfloat4*)x, ts_ws, coefI_ws,
                                          tab_ws, (vfloat4*)out, n4);
}

// Round 7
// 164.443 us; speedup vs baseline: 1.0818x; 1.0818x over previous
//
#include <hip/hip_runtime.h>

#define K_KNOTS 1024
#define N_CTRL  1021
#define TABM    4096            // buckets; ~75% contain no knot
#define TS_PAD  (K_KNOTS + 8)
#define FREE_BIT 0x8000

typedef float vfloat4 __attribute__((ext_vector_type(4)));   // nontemporal-safe

// ---------------------------------------------------------------------------
// Kernel 1: rank sort of the 1024 knots (stable, tie-safe). 16 blocks x 64.
// ---------------------------------------------------------------------------
__global__ void sort_knots_kernel(const float* __restrict__ knots,
                                  float* __restrict__ ts) {
    __shared__ __align__(16) float kl[K_KNOTS];
    const int tid = threadIdx.x;
    const int gid = blockIdx.x * blockDim.x + tid;
    for (int i = tid; i < K_KNOTS / 4; i += blockDim.x)
        ((float4*)kl)[i] = ((const float4*)knots)[i];
    __syncthreads();
    const float my = kl[gid];
    int rank = 0;
    const float4* kl4 = (const float4*)kl;
#pragma unroll 8
    for (int j4 = 0; j4 < K_KNOTS / 4; ++j4) {
        const float4 v = kl4[j4];
        const int j = j4 * 4;
        rank += (v.x < my || (v.x == my && j + 0 < gid)) ? 1 : 0;
        rank += (v.y < my || (v.y == my && j + 1 < gid)) ? 1 : 0;
        rank += (v.z < my || (v.z == my && j + 2 < gid)) ? 1 : 0;
        rank += (v.w < my || (v.w == my && j + 3 < gid)) ? 1 : 0;
    }
    ts[rank] = my;
}

// ---------------------------------------------------------------------------
// Cubic in u = x - tref carried through the de Boor recursion (prep only,
// double precision to kill cancellation for tiny knot gaps).
// ---------------------------------------------------------------------------
struct PolyD { double c0, c1, c2, c3; };

__device__ __forceinline__ PolyD lerp_poly(const PolyD dl, const PolyD dr,
                                           double tl, double tr, double tref) {
    const double inv = 1.0 / (tr - tl);
    const double A = (tref - tl) * inv;
    const double e0 = dr.c0 - dl.c0, e1 = dr.c1 - dl.c1;
    const double e2 = dr.c2 - dl.c2, e3 = dr.c3 - dl.c3;
    PolyD o;
    o.c0 = dl.c0 + A * e0;
    o.c1 = dl.c1 + A * e1 + inv * e0;
    o.c2 = dl.c2 + A * e2 + inv * e1;
    o.c3 = dl.c3 + A * e3 + inv * e2;
    return o;
}

// cubic for interval s (ts[s-1] < x <= ts[s], s in [4,1020]) centered at tref
__device__ __forceinline__ float4 interval_poly(const float* tss,
                                                const float* __restrict__ c,
                                                int s, double tref) {
    const double T0 = tss[s - 3], T1 = tss[s - 2], T2 = tss[s - 1];
    const double T3 = tss[s],     T4 = tss[s + 1], T5 = tss[s + 2];
    PolyD d0 = {(double)c[s - 4], 0, 0, 0}, d1 = {(double)c[s - 3], 0, 0, 0};
    PolyD d2 = {(double)c[s - 2], 0, 0, 0}, d3 = {(double)c[s - 1], 0, 0, 0};
    d3 = lerp_poly(d2, d3, T2, T5, tref);   // r=1
    d2 = lerp_poly(d1, d2, T1, T4, tref);
    d1 = lerp_poly(d0, d1, T0, T3, tref);
    d3 = lerp_poly(d2, d3, T2, T4, tref);   // r=2
    d2 = lerp_poly(d1, d2, T1, T3, tref);
    d3 = lerp_poly(d2, d3, T2, T3, tref);   // r=3
    return make_float4((float)d3.c0, (float)d3.c1, (float)d3.c2, (float)d3.c3);
}

// ---------------------------------------------------------------------------
// Kernel 2 (prep), 20 blocks x 256:
//  threads 0..1023   -> coef[s]: interval cubic centered at grid point
//                       gm = m/4096, m = round(ts[s]*4096), m packed into the
//                       low 13 mantissa bits of c3 (<=2^-10 rel perturbation).
//  threads 1024..5119-> tab[b] = s_lo | FREE_BIT if no knot in [Lb-eps,Rb+eps)
//                       else s_lo (clamped) as the fallback scan start.
// ---------------------------------------------------------------------------
__device__ __forceinline__ int lower_bound_s(const float* tss, float v) {
    int lo = 0, hi = K_KNOTS;
    while (lo < hi) {
        const int mid = (lo + hi) >> 1;
        if (tss[mid] < v) lo = mid + 1; else hi = mid;
    }
    return lo;
}

__global__ void prep_kernel(const float* __restrict__ ts,
                            const float* __restrict__ c,
                            float4* __restrict__ coefI,
                            unsigned short* __restrict__ tab) {
    __shared__ float tss[K_KNOTS];
    const int tid = threadIdx.x;
    for (int i = tid; i < K_KNOTS; i += blockDim.x) tss[i] = ts[i];
    __syncthreads();

    const int g = blockIdx.x * blockDim.x + tid;   // 0..5119
    if (g < K_KNOTS) {
        const int s = g;
        float4 out = make_float4(0.f, 0.f, 0.f, 0.f);
        if (s >= 4 && s <= 1020) {
            int m = (int)((double)tss[s] * (double)TABM + 0.5);
            m = m < 0 ? 0 : (m > TABM ? TABM : m);           // fits 13 bits
            const double gm = (double)m * (1.0 / (double)TABM);
            float4 p = interval_poly(tss, c, s, gm);
            const unsigned int wb =
                (__float_as_uint(p.w) & ~0x1FFFu) | (unsigned int)m;
            p.w = __uint_as_float(wb);
            out = p;
        }
        coefI[s] = out;
    } else {
        const int b = g - K_KNOTS;                 // 0..4095
        const float eps = 1e-6f;
        const float Lb = (float)b * (1.0f / (float)TABM) - eps;
        const float Rb = (float)(b + 1) * (1.0f / (float)TABM) + eps;
        const int lo1 = lower_bound_s(tss, Lb);
        const int lo2 = lower_bound_s(tss, Rb);
        const int sc = lo1 < 4 ? 4 : (lo1 > 1020 ? 1020 : lo1);  // safety clamp
        unsigned short h = (unsigned short)sc;
        if (lo1 == lo2 && lo1 >= 4 && lo1 <= 1020) h |= FREE_BIT;
        tab[b] = h;
    }
}

// ---------------------------------------------------------------------------
// Kernel 3: evaluation. Fast path (~75% of lanes): ds_read_u16 (tab) ->
// ds_read_b128 (coef) -> Horner; u = fma(m, -2^-12, x) from packed bits.
// Fallback (~25%): 3 branchless LDS steps (cover buckets with <=3 knots,
// >99% of fallback lanes); residual while-loop hits ~0.2% of lanes so only
// ~15% of waves execute any loop iteration. +inf pad bounds everything.
// Domain guarantees x in (ts[3], ts[1020]) subset (0,1) -> b in [0,4095].
// ---------------------------------------------------------------------------
__device__ __forceinline__ float eval_one(float x,
                                          const unsigned short* __restrict__ tab,
                                          const float4* __restrict__ cs,
                                          const float* __restrict__ ts) {
    const int b = (int)(x * (float)TABM);
    const unsigned short h = tab[b];
    int s = h & 0x7FFF;
    if (!(h & FREE_BIT)) {
        s += (ts[s] < x) ? 1 : 0;
        s += (ts[s] < x) ? 1 : 0;
        s += (ts[s] < x) ? 1 : 0;
        while (ts[s] < x) ++s;              // ~0.2% of lanes; pad bounds it
    }
    const float4 e = cs[s];
    const int m = (int)(__float_as_uint(e.w) & 0x1FFFu);
    const float u = __builtin_fmaf((float)m, -1.0f / (float)TABM, x);
    return e.x + u * (e.y + u * (e.z + u * e.w));
}

__global__ __launch_bounds__(256) void eval_kernel(
        const vfloat4* __restrict__ x4,
        const float* __restrict__ ts_g,
        const float4* __restrict__ coefI_g,
        const unsigned short* __restrict__ tab_g,
        vfloat4* __restrict__ out4, int n4) {
    __shared__ __align__(16) unsigned short tab_s[TABM];    // 8 KB
    __shared__ __align__(16) float4 coefI_s[K_KNOTS];       // 16 KB
    __shared__ __align__(16) float ts_s[TS_PAD];            // ~4 KB (28 KB tot)
    const int tid = threadIdx.x;

#pragma unroll
    for (int i = tid; i < TABM * 2 / 16; i += 256)
        ((uint4*)tab_s)[i] = ((const uint4*)tab_g)[i];
#pragma unroll
    for (int i = tid; i < K_KNOTS; i += 256) coefI_s[i] = coefI_g[i];
    for (int i = tid; i < TS_PAD; i += 256)
        ts_s[i] = (i < K_KNOTS) ? ts_g[i] : 1e30f;
    __syncthreads();

    const int gid    = blockIdx.x * 256 + tid;
    const int stride = gridDim.x * 256;
    for (int i = gid; i < n4; i += 4 * stride) {
        const int ib = i + stride, ic = i + 2 * stride, id = i + 3 * stride;
        const bool hb = ib < n4, hc = ic < n4, hd = id < n4;
        const vfloat4 xa = __builtin_nontemporal_load(&x4[i]);
        const vfloat4 xb = hb ? __builtin_nontemporal_load(&x4[ib]) : xa;
        const vfloat4 xc = hc ? __builtin_nontemporal_load(&x4[ic]) : xa;
        const vfloat4 xd = hd ? __builtin_nontemporal_load(&x4[id]) : xa;
        vfloat4 ra, rb, rc, rd;
        ra.x = eval_one(xa.x, tab_s, coefI_s, ts_s);
        ra.y = eval_one(xa.y, tab_s, coefI_s, ts_s);
        ra.z = eval_one(xa.z, tab_s, coefI_s, ts_s);
        ra.w = eval_one(xa.w, tab_s, coefI_s, ts_s);
        rb.x = eval_one(xb.x, tab_s, coefI_s, ts_s);
        rb.y = eval_one(xb.y, tab_s, coefI_s, ts_s);
        rb.z = eval_one(xb.z, tab_s, coefI_s, ts_s);
        rb.w = eval_one(xb.w, tab_s, coefI_s, ts_s);
        rc.x = eval_one(xc.x, tab_s, coefI_s, ts_s);
        rc.y = eval_one(xc.y, tab_s, coefI_s, ts_s);
        rc.z = eval_one(xc.z, tab_s, coefI_s, ts_s);
        rc.w = eval_one(xc.w, tab_s, coefI_s, ts_s);
        rd.x = eval_one(xd.x, tab_s, coefI_s, ts_s);
        rd.y = eval_one(xd.y, tab_s, coefI_s, ts_s);
        rd.z = eval_one(xd.z, tab_s, coefI_s, ts_s);
        rd.w = eval_one(xd.w, tab_s, coefI_s, ts_s);
        __builtin_nontemporal_store(ra, &out4[i]);
        if (hb) __builtin_nontemporal_store(rb, &out4[ib]);
        if (hc) __builtin_nontemporal_store(rc, &out4[ic]);
        if (hd) __builtin_nontemporal_store(rd, &out4[id]);
    }
}

extern "C" void kernel_launch(void* const* d_in, const int* in_sizes, int n_in,
                              void* d_out, int out_size, void* d_ws, size_t ws_size,
                              hipStream_t stream) {
    const float* x     = (const float*)d_in[0];  // [16777216]
    const float* knots = (const float*)d_in[1];  // [1024] unsorted
    const float* c     = (const float*)d_in[2];  // [1021]
    float* out = (float*)d_out;

    // ws layout: ts @0 (4 KB) | coefI @8K (16 KB) | tab @24K (8 KB)
    float*  ts_ws    = (float*)d_ws;
    float4* coefI_ws = (float4*)((char*)d_ws + 8192);
    unsigned short* tab_ws = (unsigned short*)((char*)d_ws + 8192 + 16384);

    sort_knots_kernel<<<16, 64, 0, stream>>>(knots, ts_ws);
    prep_kernel<<<(K_KNOTS + TABM) / 256, 256, 0, stream>>>(ts_ws, c, coefI_ws, tab_ws);

    const int n4 = out_size / 4;   // 4,194,304
    // 1280 blocks = 5 resident blocks/CU x 256 CUs (28 KB LDS -> 5 blocks/CU)
    eval_kernel<<<1280, 256, 0, stream>>>((const vfloat4*)x, ts_ws, coefI_ws,
                                          tab_ws, (vfloat4*)out, n4);
}

// Round 8
// 159.364 us; speedup vs baseline: 1.1163x; 1.0319x over previous
//
#include <hip/hip_runtime.h>

#define K_KNOTS 1024
#define N_CTRL  1021
#define TABM    4096            // buckets; ~75% contain no knot
#define TS_PAD  (K_KNOTS + 8)
#define FREE_BIT 0x8000

typedef float vfloat4 __attribute__((ext_vector_type(4)));   // nontemporal-safe

// ---------------------------------------------------------------------------
// Kernel 1: rank sort of the 1024 knots (stable, tie-safe). 16 blocks x 64.
// ---------------------------------------------------------------------------
__global__ void sort_knots_kernel(const float* __restrict__ knots,
                                  float* __restrict__ ts) {
    __shared__ __align__(16) float kl[K_KNOTS];
    const int tid = threadIdx.x;
    const int gid = blockIdx.x * blockDim.x + tid;
    for (int i = tid; i < K_KNOTS / 4; i += blockDim.x)
        ((float4*)kl)[i] = ((const float4*)knots)[i];
    __syncthreads();
    const float my = kl[gid];
    int rank = 0;
    const float4* kl4 = (const float4*)kl;
#pragma unroll 8
    for (int j4 = 0; j4 < K_KNOTS / 4; ++j4) {
        const float4 v = kl4[j4];
        const int j = j4 * 4;
        rank += (v.x < my || (v.x == my && j + 0 < gid)) ? 1 : 0;
        rank += (v.y < my || (v.y == my && j + 1 < gid)) ? 1 : 0;
        rank += (v.z < my || (v.z == my && j + 2 < gid)) ? 1 : 0;
        rank += (v.w < my || (v.w == my && j + 3 < gid)) ? 1 : 0;
    }
    ts[rank] = my;
}

// ---------------------------------------------------------------------------
// Cubic in u = x - tref carried through the de Boor recursion (prep only,
// double precision to kill cancellation for tiny knot gaps).
// ---------------------------------------------------------------------------
struct PolyD { double c0, c1, c2, c3; };

__device__ __forceinline__ PolyD lerp_poly(const PolyD dl, const PolyD dr,
                                           double tl, double tr, double tref) {
    const double inv = 1.0 / (tr - tl);
    const double A = (tref - tl) * inv;
    const double e0 = dr.c0 - dl.c0, e1 = dr.c1 - dl.c1;
    const double e2 = dr.c2 - dl.c2, e3 = dr.c3 - dl.c3;
    PolyD o;
    o.c0 = dl.c0 + A * e0;
    o.c1 = dl.c1 + A * e1 + inv * e0;
    o.c2 = dl.c2 + A * e2 + inv * e1;
    o.c3 = dl.c3 + A * e3 + inv * e2;
    return o;
}

// cubic for interval s (ts[s-1] < x <= ts[s], s in [4,1020]) centered at tref
__device__ __forceinline__ float4 interval_poly(const float* tss,
                                                const float* __restrict__ c,
                                                int s, double tref) {
    const double T0 = tss[s - 3], T1 = tss[s - 2], T2 = tss[s - 1];
    const double T3 = tss[s],     T4 = tss[s + 1], T5 = tss[s + 2];
    PolyD d0 = {(double)c[s - 4], 0, 0, 0}, d1 = {(double)c[s - 3], 0, 0, 0};
    PolyD d2 = {(double)c[s - 2], 0, 0, 0}, d3 = {(double)c[s - 1], 0, 0, 0};
    d3 = lerp_poly(d2, d3, T2, T5, tref);   // r=1
    d2 = lerp_poly(d1, d2, T1, T4, tref);
    d1 = lerp_poly(d0, d1, T0, T3, tref);
    d3 = lerp_poly(d2, d3, T2, T4, tref);   // r=2
    d2 = lerp_poly(d1, d2, T1, T3, tref);
    d3 = lerp_poly(d2, d3, T2, T3, tref);   // r=3
    return make_float4((float)d3.c0, (float)d3.c1, (float)d3.c2, (float)d3.c3);
}

// ---------------------------------------------------------------------------
// Kernel 2 (prep), 20 blocks x 256:
//  threads 0..1023   -> coef[s]: interval cubic centered at the grid point
//                       gm = m/4096, m = round(ts[s]*4096); m packed into the
//                       low 13 mantissa bits of c3 (<=2^-10 rel perturbation).
//  threads 1024..5119-> tab[b] = s_lo | FREE_BIT if no knot in
//                       [Lb-eps, Rb+eps) (then every x mapping to b has
//                       count s_lo); else s_lo as fallback scan start.
// ---------------------------------------------------------------------------
__device__ __forceinline__ int lower_bound_s(const float* tss, float v) {
    int lo = 0, hi = K_KNOTS;
    while (lo < hi) {
        const int mid = (lo + hi) >> 1;
        if (tss[mid] < v) lo = mid + 1; else hi = mid;
    }
    return lo;
}

__global__ void prep_kernel(const float* __restrict__ ts,
                            const float* __restrict__ c,
                            float4* __restrict__ coefI,
                            unsigned short* __restrict__ tab) {
    __shared__ float tss[K_KNOTS];
    const int tid = threadIdx.x;
    for (int i = tid; i < K_KNOTS; i += blockDim.x) tss[i] = ts[i];
    __syncthreads();

    const int g = blockIdx.x * blockDim.x + tid;   // 0..5119
    if (g < K_KNOTS) {
        const int s = g;
        float4 out = make_float4(0.f, 0.f, 0.f, 0.f);
        if (s >= 4 && s <= 1020) {
            int m = (int)((double)tss[s] * (double)TABM + 0.5);
            m = m < 0 ? 0 : (m > TABM ? TABM : m);           // fits 13 bits
            const double gm = (double)m * (1.0 / (double)TABM);
            float4 p = interval_poly(tss, c, s, gm);
            const unsigned int wb =
                (__float_as_uint(p.w) & ~0x1FFFu) | (unsigned int)m;
            p.w = __uint_as_float(wb);
            out = p;
        }
        coefI[s] = out;
    } else {
        const int b = g - K_KNOTS;                 // 0..4095
        const float eps = 1e-6f;
        const float Lb = (float)b * (1.0f / (float)TABM) - eps;
        const float Rb = (float)(b + 1) * (1.0f / (float)TABM) + eps;
        const int lo1 = lower_bound_s(tss, Lb);
        const int lo2 = lower_bound_s(tss, Rb);
        const int sc = lo1 < 4 ? 4 : (lo1 > 1020 ? 1020 : lo1);  // safety clamp
        unsigned short h = (unsigned short)sc;
        if (lo1 == lo2 && lo1 >= 4 && lo1 <= 1020) h |= FREE_BIT;
        tab[b] = h;
    }
}

// ---------------------------------------------------------------------------
// Kernel 3: evaluation. Fast path (~75% of lanes): ds_read_u16 (tab) ->
// ds_read_b128 (coef) -> Horner; u = fma(m, -2^-12, x) from packed bits.
// Fallback: scan ts from s_lo (expected ~1.3 reads), same coef read.
// Domain guarantees x in (ts[3], ts[1020]) subset (0,1) -> b in [0,4095].
// ---------------------------------------------------------------------------
__device__ __forceinline__ float eval_one(float x,
                                          const unsigned short* __restrict__ tab,
                                          const float4* __restrict__ cs,
                                          const float* __restrict__ ts) {
    const int b = (int)(x * (float)TABM);
    const unsigned short h = tab[b];
    int s = h & 0x7FFF;
    if (!(h & FREE_BIT)) {
        float t = ts[s];
        while (t < x) { ++s; t = ts[s]; }   // +inf pad bounds the scan
    }
    const float4 e = cs[s];
    const int m = (int)(__float_as_uint(e.w) & 0x1FFFu);
    const float u = __builtin_fmaf((float)m, -1.0f / (float)TABM, x);
    return e.x + u * (e.y + u * (e.z + u * e.w));
}

__global__ __launch_bounds__(256) void eval_kernel(
        const vfloat4* __restrict__ x4,
        const float* __restrict__ ts_g,
        const float4* __restrict__ coefI_g,
        const unsigned short* __restrict__ tab_g,
        vfloat4* __restrict__ out4, int n4) {
    __shared__ __align__(16) unsigned short tab_s[TABM];    // 8 KB
    __shared__ __align__(16) float4 coefI_s[K_KNOTS];       // 16 KB
    __shared__ __align__(16) float ts_s[TS_PAD];            // ~4 KB (28 KB tot)
    const int tid = threadIdx.x;

#pragma unroll
    for (int i = tid; i < TABM * 2 / 16; i += 256)
        ((uint4*)tab_s)[i] = ((const uint4*)tab_g)[i];
#pragma unroll
    for (int i = tid; i < K_KNOTS; i += 256) coefI_s[i] = coefI_g[i];
    for (int i = tid; i < TS_PAD; i += 256)
        ts_s[i] = (i < K_KNOTS) ? ts_g[i] : 1e30f;
    __syncthreads();

    const int gid    = blockIdx.x * 256 + tid;
    const int stride = gridDim.x * 256;
    for (int i = gid; i < n4; i += 2 * stride) {
        const int i2 = i + stride;
        const bool has2 = i2 < n4;
        const vfloat4 xa = __builtin_nontemporal_load(&x4[i]);
        const vfloat4 xb = has2 ? __builtin_nontemporal_load(&x4[i2]) : xa;
        vfloat4 ra, rb;
        ra.x = eval_one(xa.x, tab_s, coefI_s, ts_s);
        ra.y = eval_one(xa.y, tab_s, coefI_s, ts_s);
        ra.z = eval_one(xa.z, tab_s, coefI_s, ts_s);
        ra.w = eval_one(xa.w, tab_s, coefI_s, ts_s);
        rb.x = eval_one(xb.x, tab_s, coefI_s, ts_s);
        rb.y = eval_one(xb.y, tab_s, coefI_s, ts_s);
        rb.z = eval_one(xb.z, tab_s, coefI_s, ts_s);
        rb.w = eval_one(xb.w, tab_s, coefI_s, ts_s);
        __builtin_nontemporal_store(ra, &out4[i]);
        if (has2) __builtin_nontemporal_store(rb, &out4[i2]);
    }
}

extern "C" void kernel_launch(void* const* d_in, const int* in_sizes, int n_in,
                              void* d_out, int out_size, void* d_ws, size_t ws_size,
                              hipStream_t stream) {
    const float* x     = (const float*)d_in[0];  // [16777216]
    const float* knots = (const float*)d_in[1];  // [1024] unsorted
    const float* c     = (const float*)d_in[2];  // [1021]
    float* out = (float*)d_out;

    // ws layout: ts @0 (4 KB) | coefI @4K (16 KB) | tab @20K (8 KB)
    float*  ts_ws    = (float*)d_ws;
    float4* coefI_ws = (float4*)((char*)d_ws + 4096);
    unsigned short* tab_ws = (unsigned short*)((char*)d_ws + 4096 + 16384);

    sort_knots_kernel<<<16, 64, 0, stream>>>(knots, ts_ws);
    prep_kernel<<<(K_KNOTS + TABM) / 256, 256, 0, stream>>>(ts_ws, c, coefI_ws, tab_ws);

    const int n4 = out_size / 4;   // 4,194,304
    // 1280 blocks = 5 resident blocks/CU x 256 CUs (28 KB LDS -> 5 blocks/CU)
    eval_kernel<<<1280, 256, 0, stream>>>((const vfloat4*)x, ts_ws, coefI_ws,
                                          tab_ws, (vfloat4*)out, n4);
}